// Round 5
// baseline (210.986 us; speedup 1.0000x reference)
//
#include <hip/hip_runtime.h>

// YOLO v1 loss, B=16384, S=7, C=30. 192.7 MB read -> 1 float.
// R1 73.8us strided (VGPR=40, shallow MLP); R2 76.6us VGPR->LDS; R3 95.7us
// DMA->LDS + atomic tail; R4 69.9us DMA->LDS, no atomics. All share a ~70us
// floor with every pipe idle -> exposed latency, phase-aligned waves
// (vmcnt(0)+barrier per block) and/or shallow per-thread concurrency.
// R5: one-shot, 2 adjacent cells/thread (240 B = 15 aligned float4/array),
// 30 independent float4 loads back-to-back into registers, NO LDS, NO
// barrier, no atomics. Per-thread 480 B in flight; phases free-run.

#define NS 7
#define NC 30
#define GRID1 1568                   // 1568*256 threads * 2 cells = 802816
#define BLOCK 256

__device__ __forceinline__ float cell_loss(const float* __restrict__ p,
                                           const float* __restrict__ t,
                                           float gi, float gj)
{
    const float STEP = 1.0f / 7.0f;
    const float L_COORD = 5.0f;
    const float L_NOOBJ = 0.5f;

    // _convert_box: target, pred box1 (0:4), pred box2 (5:9)
    float cx = (t[0] + gi) * STEP;
    float cy = (t[1] + gj) * STEP;
    float ta = fmaxf(cx - t[2] * 0.5f, 0.0f);
    float tb = fmaxf(cy - t[3] * 0.5f, 0.0f);
    float tc = fminf(cx + t[2] * 0.5f, 1.0f);
    float td = fminf(cy + t[3] * 0.5f, 1.0f);

    cx = (p[0] + gi) * STEP;
    cy = (p[1] + gj) * STEP;
    float q1 = fmaxf(cx - p[2] * 0.5f, 0.0f);
    float w1 = fmaxf(cy - p[3] * 0.5f, 0.0f);
    float e1 = fminf(cx + p[2] * 0.5f, 1.0f);
    float r1 = fminf(cy + p[3] * 0.5f, 1.0f);

    cx = (p[5] + gi) * STEP;
    cy = (p[6] + gj) * STEP;
    float q2 = fmaxf(cx - p[7] * 0.5f, 0.0f);
    float w2 = fmaxf(cy - p[8] * 0.5f, 0.0f);
    float e2 = fminf(cx + p[7] * 0.5f, 1.0f);
    float r2 = fminf(cy + p[8] * 0.5f, 1.0f);

    float tarea = (td - tb) * (tc - ta);
    // _iou: inter NOT clamped; iou = inter>0 ? inter/(union+1e-5) : 0
    float minx = fmaxf(ta, q1), miny = fmaxf(tb, w1);
    float maxx = fminf(tc, e1), maxy = fminf(td, r1);
    float inter = (maxy - miny) * (maxx - minx);
    float uni = (e1 - q1) * (r1 - w1) + tarea - inter;
    float iou1 = (inter > 0.0f) ? inter / (uni + 1e-5f) : 0.0f;

    minx = fmaxf(ta, q2); miny = fmaxf(tb, w2);
    maxx = fminf(tc, e2); maxy = fminf(td, r2);
    inter = (maxy - miny) * (maxx - minx);
    uni = (e2 - q2) * (r2 - w2) + tarea - inter;
    float iou2 = (inter > 0.0f) ? inter / (uni + 1e-5f) : 0.0f;

    bool sel2 = (iou1 <= iou2);
    float conf_t = sel2 ? iou2 : iou1;
    float px = sel2 ? p[5] : p[0];
    float py = sel2 ? p[6] : p[1];
    float pw = sel2 ? p[7] : p[2];
    float ph = sel2 ? p[8] : p[3];
    float pconf = sel2 ? p[9] : p[4];

    float obj = (t[4] > 0.0f) ? 1.0f : 0.0f;
    float noobj = (t[4] == 0.0f) ? 1.0f : 0.0f;

    float dx = px - t[0], dy = py - t[1];
    float dw = pw - t[2], dh = ph - t[3];
    float coord = dx * dx + dy * dy + dw * dw + dh * dh;

    float dc = pconf - conf_t;
    float obj_loss = dc * dc;

    float cls = 0.0f;
    #pragma unroll
    for (int k = 10; k < NC; ++k) {
        float d = p[k] - t[k];
        cls += d * d;
    }

    float d4 = p[4] - t[4];
    float d9 = p[9] - t[9];
    float noobj_loss = d4 * d4 + d9 * d9;

    return obj * (obj_loss + L_COORD * coord + cls) + L_NOOBJ * noobj * noobj_loss;
}

__global__ __launch_bounds__(BLOCK) void yolo_loss_stage1(
    const float* __restrict__ pred,
    const float* __restrict__ targ,
    float* __restrict__ partials)
{
    const int tid = threadIdx.x;
    const int task = blockIdx.x * BLOCK + tid;   // one task = 2 adjacent cells
    const int cell0 = task * 2;

    // 240 B per task per array = 15 aligned float4. Issue all 30 loads
    // back-to-back (independent) before any use.
    const float4* __restrict__ gp4 = (const float4*)pred + (size_t)task * 15;
    const float4* __restrict__ gt4 = (const float4*)targ + (size_t)task * 15;

    float p[2 * NC], t[2 * NC];
    #pragma unroll
    for (int k = 0; k < 15; ++k) {
        float4 v = gp4[k];
        p[4 * k + 0] = v.x; p[4 * k + 1] = v.y; p[4 * k + 2] = v.z; p[4 * k + 3] = v.w;
    }
    #pragma unroll
    for (int k = 0; k < 15; ++k) {
        float4 u = gt4[k];
        t[4 * k + 0] = u.x; t[4 * k + 1] = u.y; t[4 * k + 2] = u.z; t[4 * k + 3] = u.w;
    }

    // grid coords for the two cells (cell = ((b*7)+i)*7 + j)
    int j0 = cell0 % NS;
    int i0 = (cell0 / NS) % NS;
    int c1 = cell0 + 1;
    int j1 = c1 % NS;
    int i1 = (c1 / NS) % NS;

    float lsum = cell_loss(p, t, (float)i0, (float)j0)
               + cell_loss(p + NC, t + NC, (float)i1, (float)j1);

    // wave(64) shuffle reduce
    #pragma unroll
    for (int off = 32; off > 0; off >>= 1)
        lsum += __shfl_down(lsum, off, 64);

    __shared__ float wsum[4];
    int lane = tid & 63;
    int wid = tid >> 6;
    if (lane == 0) wsum[wid] = lsum;
    __syncthreads();
    if (tid == 0)
        partials[blockIdx.x] = (wsum[0] + wsum[1]) + (wsum[2] + wsum[3]);
}

__global__ __launch_bounds__(256) void yolo_loss_stage2(
    const float* __restrict__ partials, float* __restrict__ out, float inv_B)
{
    const int tid = threadIdx.x;
    float s = 0.0f;
    for (int k = tid; k < GRID1; k += 256)
        s += partials[k];

    #pragma unroll
    for (int off = 32; off > 0; off >>= 1)
        s += __shfl_down(s, off, 64);

    __shared__ float wsum[4];
    int lane = tid & 63;
    int wid = tid >> 6;
    if (lane == 0) wsum[wid] = s;
    __syncthreads();
    if (tid == 0)
        out[0] = (wsum[0] + wsum[1] + wsum[2] + wsum[3]) * inv_B;
}

extern "C" void kernel_launch(void* const* d_in, const int* in_sizes, int n_in,
                              void* d_out, int out_size, void* d_ws, size_t ws_size,
                              hipStream_t stream) {
    const float* pred = (const float*)d_in[0];
    const float* targ = (const float*)d_in[1];
    float* out = (float*)d_out;
    float* partials = (float*)d_ws;          // 1568 floats scratch

    const float inv_B = 1.0f / 16384.0f;

    yolo_loss_stage1<<<GRID1, BLOCK, 0, stream>>>(pred, targ, partials);
    yolo_loss_stage2<<<1, 256, 0, stream>>>(partials, out, inv_B);
}

// Round 6
// 206.738 us; speedup vs baseline: 1.0205x; 1.0205x over previous
//
#include <hip/hip_runtime.h>

// YOLO v1 loss, B=16384, S=7, C=30. 192.7 MB read -> 1 float.
// R1-R5 all plateau 70-96us, all pipes <20%. R5 showed VGPR=68: the compiler
// serialized the "30 loads in flight" plan (default launch_bounds caps regs).
// R6: force the experiment to actually run -- __launch_bounds__(256,1) for a
// 512-VGPR budget, load into float4 arrays, sched_barrier(0) so the 30
// independent loads issue before ANY consumer. No LDS, no barrier, no atomics.

#define NS 7
#define NC 30
#define GRID1 1568                   // 1568*256 threads * 2 cells = 802816
#define BLOCK 256

__device__ __forceinline__ float cell_loss(const float* __restrict__ p,
                                           const float* __restrict__ t,
                                           float gi, float gj)
{
    const float STEP = 1.0f / 7.0f;
    const float L_COORD = 5.0f;
    const float L_NOOBJ = 0.5f;

    // _convert_box: target, pred box1 (0:4), pred box2 (5:9)
    float cx = (t[0] + gi) * STEP;
    float cy = (t[1] + gj) * STEP;
    float ta = fmaxf(cx - t[2] * 0.5f, 0.0f);
    float tb = fmaxf(cy - t[3] * 0.5f, 0.0f);
    float tc = fminf(cx + t[2] * 0.5f, 1.0f);
    float td = fminf(cy + t[3] * 0.5f, 1.0f);

    cx = (p[0] + gi) * STEP;
    cy = (p[1] + gj) * STEP;
    float q1 = fmaxf(cx - p[2] * 0.5f, 0.0f);
    float w1 = fmaxf(cy - p[3] * 0.5f, 0.0f);
    float e1 = fminf(cx + p[2] * 0.5f, 1.0f);
    float r1 = fminf(cy + p[3] * 0.5f, 1.0f);

    cx = (p[5] + gi) * STEP;
    cy = (p[6] + gj) * STEP;
    float q2 = fmaxf(cx - p[7] * 0.5f, 0.0f);
    float w2 = fmaxf(cy - p[8] * 0.5f, 0.0f);
    float e2 = fminf(cx + p[7] * 0.5f, 1.0f);
    float r2 = fminf(cy + p[8] * 0.5f, 1.0f);

    float tarea = (td - tb) * (tc - ta);
    // _iou: inter NOT clamped; iou = inter>0 ? inter/(union+1e-5) : 0
    float minx = fmaxf(ta, q1), miny = fmaxf(tb, w1);
    float maxx = fminf(tc, e1), maxy = fminf(td, r1);
    float inter = (maxy - miny) * (maxx - minx);
    float uni = (e1 - q1) * (r1 - w1) + tarea - inter;
    float iou1 = (inter > 0.0f) ? inter / (uni + 1e-5f) : 0.0f;

    minx = fmaxf(ta, q2); miny = fmaxf(tb, w2);
    maxx = fminf(tc, e2); maxy = fminf(td, r2);
    inter = (maxy - miny) * (maxx - minx);
    uni = (e2 - q2) * (r2 - w2) + tarea - inter;
    float iou2 = (inter > 0.0f) ? inter / (uni + 1e-5f) : 0.0f;

    bool sel2 = (iou1 <= iou2);
    float conf_t = sel2 ? iou2 : iou1;
    float px = sel2 ? p[5] : p[0];
    float py = sel2 ? p[6] : p[1];
    float pw = sel2 ? p[7] : p[2];
    float ph = sel2 ? p[8] : p[3];
    float pconf = sel2 ? p[9] : p[4];

    float obj = (t[4] > 0.0f) ? 1.0f : 0.0f;
    float noobj = (t[4] == 0.0f) ? 1.0f : 0.0f;

    float dx = px - t[0], dy = py - t[1];
    float dw = pw - t[2], dh = ph - t[3];
    float coord = dx * dx + dy * dy + dw * dw + dh * dh;

    float dc = pconf - conf_t;
    float obj_loss = dc * dc;

    float cls = 0.0f;
    #pragma unroll
    for (int k = 10; k < NC; ++k) {
        float d = p[k] - t[k];
        cls += d * d;
    }

    float d4 = p[4] - t[4];
    float d9 = p[9] - t[9];
    float noobj_loss = d4 * d4 + d9 * d9;

    return obj * (obj_loss + L_COORD * coord + cls) + L_NOOBJ * noobj * noobj_loss;
}

__global__ __launch_bounds__(BLOCK, 1) void yolo_loss_stage1(
    const float* __restrict__ pred,
    const float* __restrict__ targ,
    float* __restrict__ partials)
{
    const int tid = threadIdx.x;
    const int task = blockIdx.x * BLOCK + tid;   // one task = 2 adjacent cells
    const int cell0 = task * 2;

    const float4* __restrict__ gp4 = (const float4*)pred + (size_t)task * 15;
    const float4* __restrict__ gt4 = (const float4*)targ + (size_t)task * 15;

    // Issue ALL 30 independent 16B loads before any consumer. launch_bounds
    // (256,1) gives the allocator a 512-VGPR budget (~130 needed).
    float4 vp[15], vt[15];
    #pragma unroll
    for (int k = 0; k < 15; ++k) vp[k] = gp4[k];
    #pragma unroll
    for (int k = 0; k < 15; ++k) vt[k] = gt4[k];
    __builtin_amdgcn_sched_barrier(0);   // loads must not sink below this

    float p[2 * NC], t[2 * NC];
    #pragma unroll
    for (int k = 0; k < 15; ++k) {
        p[4 * k + 0] = vp[k].x; p[4 * k + 1] = vp[k].y;
        p[4 * k + 2] = vp[k].z; p[4 * k + 3] = vp[k].w;
        t[4 * k + 0] = vt[k].x; t[4 * k + 1] = vt[k].y;
        t[4 * k + 2] = vt[k].z; t[4 * k + 3] = vt[k].w;
    }

    // grid coords for the two cells (cell = ((b*7)+i)*7 + j)
    int j0 = cell0 % NS;
    int i0 = (cell0 / NS) % NS;
    int c1 = cell0 + 1;
    int j1 = c1 % NS;
    int i1 = (c1 / NS) % NS;

    float lsum = cell_loss(p, t, (float)i0, (float)j0)
               + cell_loss(p + NC, t + NC, (float)i1, (float)j1);

    // wave(64) shuffle reduce
    #pragma unroll
    for (int off = 32; off > 0; off >>= 1)
        lsum += __shfl_down(lsum, off, 64);

    __shared__ float wsum[4];
    int lane = tid & 63;
    int wid = tid >> 6;
    if (lane == 0) wsum[wid] = lsum;
    __syncthreads();
    if (tid == 0)
        partials[blockIdx.x] = (wsum[0] + wsum[1]) + (wsum[2] + wsum[3]);
}

__global__ __launch_bounds__(256) void yolo_loss_stage2(
    const float* __restrict__ partials, float* __restrict__ out, float inv_B)
{
    const int tid = threadIdx.x;
    float s = 0.0f;
    for (int k = tid; k < GRID1; k += 256)
        s += partials[k];

    #pragma unroll
    for (int off = 32; off > 0; off >>= 1)
        s += __shfl_down(s, off, 64);

    __shared__ float wsum[4];
    int lane = tid & 63;
    int wid = tid >> 6;
    if (lane == 0) wsum[wid] = s;
    __syncthreads();
    if (tid == 0)
        out[0] = (wsum[0] + wsum[1] + wsum[2] + wsum[3]) * inv_B;
}

extern "C" void kernel_launch(void* const* d_in, const int* in_sizes, int n_in,
                              void* d_out, int out_size, void* d_ws, size_t ws_size,
                              hipStream_t stream) {
    const float* pred = (const float*)d_in[0];
    const float* targ = (const float*)d_in[1];
    float* out = (float*)d_out;
    float* partials = (float*)d_ws;          // 1568 floats scratch

    const float inv_B = 1.0f / 16384.0f;

    yolo_loss_stage1<<<GRID1, BLOCK, 0, stream>>>(pred, targ, partials);
    yolo_loss_stage2<<<1, 256, 0, stream>>>(partials, out, inv_B);
}